// Round 1
// baseline (501.025 us; speedup 1.0000x reference)
//
#include <hip/hip_runtime.h>
#include <cstdint>
#include <cstddef>

// HyenaCascade on MI355X.
// B=2, L=8192, HID=1024 (16 heads x 64), STATE=16, K=3.
// Long conv = sum of 16 exponentials => 16-state fwd+bwd linear recurrence,
// computed with a 3-phase chunked scan (local scans -> carry combine -> apply).

#define Bn 2
#define Ln 8192
#define HIDn 1024
#define HEADSn 16
#define STATEn 16
#define THIDn 3072  // 3*HID

// load u[b, t, c] given base = &u[b,0,c]; zero outside [0,L)
__device__ __forceinline__ float ldu(const float* __restrict__ base, int t) {
    return ((unsigned)t < (unsigned)Ln) ? base[(size_t)t * THIDn] : 0.0f;
}

// ---------------- Phase A: per-chunk local scan finals ----------------
template <int CH>
__global__ __launch_bounds__(64) void hyena_phaseA(
    const float* __restrict__ u, const float* __restrict__ sfw,
    const float* __restrict__ lp,
    float* __restrict__ carryF, float* __restrict__ carryG) {
    extern __shared__ float s_x1v[];  // CH*64 floats, lane-private columns
    const int j = threadIdx.x;        // channel within head
    const int chunk = blockIdx.x;
    const int h = blockIdx.y;
    const int b = blockIdx.z;
    const int c1 = h * 192 + 64 + j;  // x1 column in u
    const int cv = c1 + 64;           // v column
    const int t0 = chunk * CH;

    const float* u1 = u + (size_t)b * Ln * THIDn + c1;
    const float* uv = u + (size_t)b * Ln * THIDn + cv;
    const float w10 = sfw[c1 * 3 + 0], w11 = sfw[c1 * 3 + 1], w12 = 2.0f * sfw[c1 * 3 + 2];
    const float wv0 = sfw[cv * 3 + 0], wv1 = sfw[cv * 3 + 1], wv2 = 2.0f * sfw[cv * 3 + 2];

    float p[STATEn];
#pragma unroll
    for (int s = 0; s < STATEn; ++s) p[s] = expf(lp[s]);

    float f[STATEn];
#pragma unroll
    for (int s = 0; s < STATEn; ++s) f[s] = 0.0f;

    // forward local scan; stash x1v in LDS for the backward local scan
    float a0 = ldu(u1, t0 - 2), a1 = ldu(u1, t0 - 1), a2 = ldu(u1, t0), a3 = ldu(u1, t0 + 1);
    float v0 = ldu(uv, t0 - 2), v1 = ldu(uv, t0 - 1), v2 = ldu(uv, t0), v3 = ldu(uv, t0 + 1);
#pragma unroll 4
    for (int tt = 0; tt < CH; ++tt) {
        const int t = t0 + tt;
        const float a4 = ldu(u1, t + 2);
        const float v4 = ldu(uv, t + 2);
        // bidirectional K=3 FIR: w0*(x[t-2]+x[t+2]) + w1*(x[t-1]+x[t+1]) + 2*w2*x[t]
        const float z1 = fmaf(w10, a0 + a4, fmaf(w11, a1 + a3, w12 * a2));
        const float zv = fmaf(wv0, v0 + v4, fmaf(wv1, v1 + v3, wv2 * v2));
        const float x = z1 * zv;
        s_x1v[tt * 64 + j] = x;
#pragma unroll
        for (int s = 0; s < STATEn; ++s) f[s] = fmaf(p[s], f[s], x);
        a0 = a1; a1 = a2; a2 = a3; a3 = a4;
        v0 = v1; v1 = v2; v2 = v3; v3 = v4;
    }
    __syncthreads();

    float g[STATEn];
#pragma unroll
    for (int s = 0; s < STATEn; ++s) g[s] = 0.0f;
#pragma unroll 4
    for (int tt = CH - 1; tt >= 0; --tt) {
        const float x = s_x1v[tt * 64 + j];
#pragma unroll
        for (int s = 0; s < STATEn; ++s) g[s] = fmaf(p[s], g[s], x);
    }

    const int i = h * 64 + j;
    const int gch = b * HIDn + i;
    const size_t base = ((size_t)chunk * (Bn * HIDn) + gch) * 16;  // chunk-major
#pragma unroll
    for (int s = 0; s < STATEn; ++s) carryF[base + s] = f[s];
#pragma unroll
    for (int s = 0; s < STATEn; ++s) carryG[base + s] = g[s];
}

// ---------------- Phase B: carry combine across chunks (in-place) ----------------
template <int CH>
__global__ __launch_bounds__(256) void hyena_phaseB(
    const float* __restrict__ lp,
    float* __restrict__ carryF, float* __restrict__ carryG) {
    constexpr int NC = Ln / CH;
    const int dir = blockIdx.x >> 7;                          // blocks 0..127 fwd, 128..255 bwd
    const int ht = ((blockIdx.x & 127) << 8) + threadIdx.x;   // 0..32767
    const int s = ht & 15;
    const int gch = ht >> 4;                                  // 0..2047
    const float pCH = expf(lp[s] * (float)CH);
    float c = 0.0f;
    if (dir == 0) {
        for (int k = 0; k < NC; ++k) {
            const size_t pos = ((size_t)k * (Bn * HIDn) + gch) * 16 + s;
            const float local = carryF[pos];
            carryF[pos] = c;                 // carry-in entering chunk k
            c = fmaf(pCH, c, local);
        }
    } else {
        for (int k = NC - 1; k >= 0; --k) {
            const size_t pos = ((size_t)k * (Bn * HIDn) + gch) * 16 + s;
            const float local = carryG[pos];
            carryG[pos] = c;                 // carry-in entering chunk k from the right
            c = fmaf(pCH, c, local);
        }
    }
}

// ---------------- Phase C: seeded scans + gating + output ----------------
template <int CH>
__global__ __launch_bounds__(64) void hyena_phaseC(
    const float* __restrict__ u, const float* __restrict__ sfw,
    const float* __restrict__ lp, const float* __restrict__ res,
    const float* __restrict__ Dp,
    const float* __restrict__ carryF, const float* __restrict__ carryG,
    float* __restrict__ out) {
    extern __shared__ float s_yc[];  // CH*64 floats, lane-private columns
    const int j = threadIdx.x;
    const int chunk = blockIdx.x;
    const int h = blockIdx.y;
    const int b = blockIdx.z;
    const int c2 = h * 192 + j;       // x2 (gate) column
    const int c1 = c2 + 64;           // x1 column
    const int cv = c2 + 128;          // v column
    const int i = h * 64 + j;
    const int gch = b * HIDn + i;
    const int t0 = chunk * CH;
    const int t1 = t0 + CH - 1;

    const float* u2 = u + (size_t)b * Ln * THIDn + c2;
    const float* u1 = u + (size_t)b * Ln * THIDn + c1;
    const float* uv = u + (size_t)b * Ln * THIDn + cv;
    const float w20 = sfw[c2 * 3 + 0], w21 = sfw[c2 * 3 + 1], w22 = 2.0f * sfw[c2 * 3 + 2];
    const float w10 = sfw[c1 * 3 + 0], w11 = sfw[c1 * 3 + 1], w12 = 2.0f * sfw[c1 * 3 + 2];
    const float wv0 = sfw[cv * 3 + 0], wv1 = sfw[cv * 3 + 1], wv2 = 2.0f * sfw[cv * 3 + 2];

    float p[STATEn], r[STATEn];
#pragma unroll
    for (int s = 0; s < STATEn; ++s) p[s] = expf(lp[s]);
#pragma unroll
    for (int s = 0; s < STATEn; ++s) r[s] = res[s];

    const size_t cbase = ((size_t)chunk * (Bn * HIDn) + gch) * 16;
    float f[STATEn];
#pragma unroll
    for (int s = 0; s < STATEn; ++s) f[s] = carryF[cbase + s];

    // ---- forward pass: causal branch, store y_c in LDS ----
    {
        float a0 = ldu(u1, t0 - 2), a1 = ldu(u1, t0 - 1), a2 = ldu(u1, t0), a3 = ldu(u1, t0 + 1);
        float v0 = ldu(uv, t0 - 2), v1 = ldu(uv, t0 - 1), v2 = ldu(uv, t0), v3 = ldu(uv, t0 + 1);
#pragma unroll 4
        for (int tt = 0; tt < CH; ++tt) {
            const int t = t0 + tt;
            const float a4 = ldu(u1, t + 2);
            const float v4 = ldu(uv, t + 2);
            const float z1 = fmaf(w10, a0 + a4, fmaf(w11, a1 + a3, w12 * a2));
            const float zv = fmaf(wv0, v0 + v4, fmaf(wv1, v1 + v3, wv2 * v2));
            const float x = z1 * zv;
#pragma unroll
            for (int s = 0; s < STATEn; ++s) f[s] = fmaf(p[s], f[s], x);
            float acc0 = r[0] * f[0], acc1 = r[1] * f[1], acc2 = r[2] * f[2], acc3 = r[3] * f[3];
#pragma unroll
            for (int s = 4; s < STATEn; s += 4) {
                acc0 = fmaf(r[s + 0], f[s + 0], acc0);
                acc1 = fmaf(r[s + 1], f[s + 1], acc1);
                acc2 = fmaf(r[s + 2], f[s + 2], acc2);
                acc3 = fmaf(r[s + 3], f[s + 3], acc3);
            }
            s_yc[tt * 64 + j] = (acc0 + acc1) + (acc2 + acc3);
            a0 = a1; a1 = a2; a2 = a3; a3 = a4;
            v0 = v1; v1 = v2; v2 = v3; v3 = v4;
        }
    }
    __syncthreads();

    // ---- backward pass: anti-causal branch + gate + store ----
    float g[STATEn];
#pragma unroll
    for (int s = 0; s < STATEn; ++s) g[s] = carryG[cbase + s];
    const float dI = Dp[i];
    {
        float a4 = ldu(u1, t1 + 2), a3 = ldu(u1, t1 + 1), a2 = ldu(u1, t1), a1 = ldu(u1, t1 - 1);
        float v4 = ldu(uv, t1 + 2), v3 = ldu(uv, t1 + 1), v2 = ldu(uv, t1), v1 = ldu(uv, t1 - 1);
        float e4 = ldu(u2, t1 + 2), e3 = ldu(u2, t1 + 1), e2 = ldu(u2, t1), e1 = ldu(u2, t1 - 1);
#pragma unroll 4
        for (int tt = CH - 1; tt >= 0; --tt) {
            const int t = t0 + tt;
            const float a0 = ldu(u1, t - 2);
            const float v0 = ldu(uv, t - 2);
            const float e0 = ldu(u2, t - 2);
            const float z1 = fmaf(w10, a0 + a4, fmaf(w11, a1 + a3, w12 * a2));
            const float zv = fmaf(wv0, v0 + v4, fmaf(wv1, v1 + v3, wv2 * v2));
            const float z2 = fmaf(w20, e0 + e4, fmaf(w21, e1 + e3, w22 * e2));
            const float x = z1 * zv;
#pragma unroll
            for (int s = 0; s < STATEn; ++s) g[s] = fmaf(p[s], g[s], x);
            float acc0 = r[0] * g[0], acc1 = r[1] * g[1], acc2 = r[2] * g[2], acc3 = r[3] * g[3];
#pragma unroll
            for (int s = 4; s < STATEn; s += 4) {
                acc0 = fmaf(r[s + 0], g[s + 0], acc0);
                acc1 = fmaf(r[s + 1], g[s + 1], acc1);
                acc2 = fmaf(r[s + 2], g[s + 2], acc2);
                acc3 = fmaf(r[s + 3], g[s + 3], acc3);
            }
            const float ya = (acc0 + acc1) + (acc2 + acc3);
            const float y = (s_yc[tt * 64 + j] + ya + dI * x) * z2;
            out[((size_t)b * Ln + t) * HIDn + i] = y;
            a4 = a3; a3 = a2; a2 = a1; a1 = a0;
            v4 = v3; v3 = v2; v2 = v1; v1 = v0;
            e4 = e3; e3 = e2; e2 = e1; e1 = e0;
        }
    }
}

template <int CH>
static void run_all(const float* u, const float* sfw, const float* lp,
                    const float* res, const float* Dp, float* out,
                    void* ws, hipStream_t stream) {
    constexpr int NC = Ln / CH;
    float* carryF = (float*)ws;
    float* carryG = carryF + (size_t)NC * (Bn * HIDn) * 16;
    dim3 grid(NC, HEADSn, Bn);
    const size_t shbytes = (size_t)CH * 64 * sizeof(float);
    hipLaunchKernelGGL((hyena_phaseA<CH>), grid, dim3(64), shbytes, stream,
                       u, sfw, lp, carryF, carryG);
    hipLaunchKernelGGL((hyena_phaseB<CH>), dim3(256), dim3(256), 0, stream,
                       lp, carryF, carryG);
    hipLaunchKernelGGL((hyena_phaseC<CH>), grid, dim3(64), shbytes, stream,
                       u, sfw, lp, res, Dp, carryF, carryG, out);
}

extern "C" void kernel_launch(void* const* d_in, const int* in_sizes, int n_in,
                              void* d_out, int out_size, void* d_ws, size_t ws_size,
                              hipStream_t stream) {
    const float* u   = (const float*)d_in[0];  // (B, L, 3*HID) fp32
    const float* sfw = (const float*)d_in[1];  // (3*HID, 1, 3)
    const float* lp  = (const float*)d_in[2];  // (1, 16, 1)
    const float* res = (const float*)d_in[3];  // (1, 16)
    const float* Dp  = (const float*)d_in[4];  // (HID,)
    float* out = (float*)d_out;                // (B, L, HID) fp32

    // carry workspace: NC * 2048 channels * 32 states * 4 B = 2^31/CH bytes
    const size_t need64 = ((size_t)1 << 31) / 64;  // 32 MiB at CH=64
    if (ws_size >= need64)            run_all<64>(u, sfw, lp, res, Dp, out, d_ws, stream);
    else if (ws_size >= need64 / 2)   run_all<128>(u, sfw, lp, res, Dp, out, d_ws, stream);
    else if (ws_size >= need64 / 4)   run_all<256>(u, sfw, lp, res, Dp, out, d_ws, stream);
    else                              run_all<512>(u, sfw, lp, res, Dp, out, d_ws, stream);
}

// Round 2
// 415.477 us; speedup vs baseline: 1.2059x; 1.2059x over previous
//
#include <hip/hip_runtime.h>
#include <cstdint>
#include <cstddef>

// HyenaCascade on MI355X — 3-phase chunked bidirectional 16-state scan.
// R1: no LDS anywhere (lane-private data stays in registers / RMW via out),
//     packed fp32 state updates (v_pk_fma_f32), batched loads in phase B.

#define Bn 2
#define Ln 8192
#define HIDn 1024
#define HEADSn 16
#define STATEn 16
#define THIDn 3072  // 3*HID

typedef __attribute__((ext_vector_type(2))) float f32x2;

// load u[b, t, c] given base = &u[b,0,c]; zero outside [0,L)
__device__ __forceinline__ float ldu(const float* __restrict__ base, int t) {
    return ((unsigned)t < (unsigned)Ln) ? base[(size_t)t * THIDn] : 0.0f;
}

// ---------------- Phase A: per-chunk local scan finals ----------------
template <int CH>
__global__ __launch_bounds__(64, 4) void hyena_phaseA(
    const float* __restrict__ u, const float* __restrict__ sfw,
    const float* __restrict__ lp,
    float* __restrict__ carryF, float* __restrict__ carryG) {
    const int j = threadIdx.x;        // channel within head
    const int chunk = blockIdx.x;
    const int h = blockIdx.y;
    const int b = blockIdx.z;
    const int c1 = h * 192 + 64 + j;  // x1 column in u
    const int cv = c1 + 64;           // v column
    const int t0 = chunk * CH;
    const int t1 = t0 + CH - 1;

    const float* u1 = u + (size_t)b * Ln * THIDn + c1;
    const float* uv = u + (size_t)b * Ln * THIDn + cv;
    const float w10 = sfw[c1 * 3 + 0], w11 = sfw[c1 * 3 + 1], w12 = 2.0f * sfw[c1 * 3 + 2];
    const float wv0 = sfw[cv * 3 + 0], wv1 = sfw[cv * 3 + 1], wv2 = 2.0f * sfw[cv * 3 + 2];

    f32x2 p2[8];
#pragma unroll
    for (int i = 0; i < 8; ++i) p2[i] = (f32x2){expf(lp[2 * i]), expf(lp[2 * i + 1])};

    const int i = h * 64 + j;
    const int gch = b * HIDn + i;
    const size_t base = ((size_t)chunk * (Bn * HIDn) + gch) * 16;  // chunk-major

    // ---- forward local scan ----
    {
        f32x2 f2[8];
#pragma unroll
        for (int s = 0; s < 8; ++s) f2[s] = (f32x2){0.0f, 0.0f};
        float a0 = ldu(u1, t0 - 2), a1 = ldu(u1, t0 - 1), a2 = ldu(u1, t0), a3 = ldu(u1, t0 + 1);
        float v0 = ldu(uv, t0 - 2), v1 = ldu(uv, t0 - 1), v2 = ldu(uv, t0), v3 = ldu(uv, t0 + 1);
#pragma unroll 8
        for (int tt = 0; tt < CH; ++tt) {
            const int t = t0 + tt;
            const float a4 = ldu(u1, t + 2);
            const float v4 = ldu(uv, t + 2);
            const float z1 = fmaf(w10, a0 + a4, fmaf(w11, a1 + a3, w12 * a2));
            const float zv = fmaf(wv0, v0 + v4, fmaf(wv1, v1 + v3, wv2 * v2));
            const float x = z1 * zv;
            const f32x2 x2 = (f32x2){x, x};
#pragma unroll
            for (int s = 0; s < 8; ++s) f2[s] = __builtin_elementwise_fma(p2[s], f2[s], x2);
            a0 = a1; a1 = a2; a2 = a3; a3 = a4;
            v0 = v1; v1 = v2; v2 = v3; v3 = v4;
        }
        f32x2* cF2 = (f32x2*)(carryF + base);
#pragma unroll
        for (int s = 0; s < 8; ++s) cF2[s] = f2[s];
    }

    // ---- backward local scan (recompute x1v; chunk data is L1/L2-hot) ----
    {
        f32x2 g2[8];
#pragma unroll
        for (int s = 0; s < 8; ++s) g2[s] = (f32x2){0.0f, 0.0f};
        float a4 = ldu(u1, t1 + 2), a3 = ldu(u1, t1 + 1), a2 = ldu(u1, t1), a1 = ldu(u1, t1 - 1);
        float v4 = ldu(uv, t1 + 2), v3 = ldu(uv, t1 + 1), v2 = ldu(uv, t1), v1 = ldu(uv, t1 - 1);
#pragma unroll 8
        for (int tt = CH - 1; tt >= 0; --tt) {
            const int t = t0 + tt;
            const float a0 = ldu(u1, t - 2);
            const float v0 = ldu(uv, t - 2);
            const float z1 = fmaf(w10, a0 + a4, fmaf(w11, a1 + a3, w12 * a2));
            const float zv = fmaf(wv0, v0 + v4, fmaf(wv1, v1 + v3, wv2 * v2));
            const float x = z1 * zv;
            const f32x2 x2 = (f32x2){x, x};
#pragma unroll
            for (int s = 0; s < 8; ++s) g2[s] = __builtin_elementwise_fma(p2[s], g2[s], x2);
            a4 = a3; a3 = a2; a2 = a1; a1 = a0;
            v4 = v3; v3 = v2; v2 = v1; v1 = v0;
        }
        f32x2* cG2 = (f32x2*)(carryG + base);
#pragma unroll
        for (int s = 0; s < 8; ++s) cG2[s] = g2[s];
    }
}

// ---------------- Phase B: carry combine across chunks (in-place) ----------------
template <int CH>
__global__ __launch_bounds__(256) void hyena_phaseB(
    const float* __restrict__ lp,
    float* __restrict__ carryF, float* __restrict__ carryG) {
    constexpr int NC = Ln / CH;
    constexpr int UB = 16;  // batched loads for MLP (NC % UB == 0 for all CH used)
    const int dir = blockIdx.x >> 7;                          // blocks 0..127 fwd, 128..255 bwd
    const int ht = ((blockIdx.x & 127) << 8) + threadIdx.x;   // 0..32767
    const int s = ht & 15;
    const int gch = ht >> 4;                                  // 0..2047
    const float pCH = expf(lp[s] * (float)CH);
    float c = 0.0f;
    if (dir == 0) {
        for (int k0 = 0; k0 < NC; k0 += UB) {
            float loc[UB];
#pragma unroll
            for (int q = 0; q < UB; ++q)
                loc[q] = carryF[((size_t)(k0 + q) * (Bn * HIDn) + gch) * 16 + s];
#pragma unroll
            for (int q = 0; q < UB; ++q) {
                carryF[((size_t)(k0 + q) * (Bn * HIDn) + gch) * 16 + s] = c;
                c = fmaf(pCH, c, loc[q]);
            }
        }
    } else {
        for (int k0 = NC - UB; k0 >= 0; k0 -= UB) {
            float loc[UB];
#pragma unroll
            for (int q = UB - 1; q >= 0; --q)
                loc[q] = carryG[((size_t)(k0 + q) * (Bn * HIDn) + gch) * 16 + s];
#pragma unroll
            for (int q = UB - 1; q >= 0; --q) {
                carryG[((size_t)(k0 + q) * (Bn * HIDn) + gch) * 16 + s] = c;
                c = fmaf(pCH, c, loc[q]);
            }
        }
    }
}

// ---------------- Phase C: seeded scans + gating + output ----------------
// fwd pass writes causal y_c to out; bwd pass does same-thread RMW:
// out = (y_c + y_a + D*x) * x2. All addresses lane-private -> no sync needed.
template <int CH>
__global__ __launch_bounds__(64, 4) void hyena_phaseC(
    const float* __restrict__ u, const float* __restrict__ sfw,
    const float* __restrict__ lp, const float* __restrict__ res,
    const float* __restrict__ Dp,
    const float* __restrict__ carryF, const float* __restrict__ carryG,
    float* __restrict__ out) {
    const int j = threadIdx.x;
    const int chunk = blockIdx.x;
    const int h = blockIdx.y;
    const int b = blockIdx.z;
    const int c2 = h * 192 + j;       // x2 (gate) column
    const int c1 = c2 + 64;           // x1 column
    const int cv = c2 + 128;          // v column
    const int i = h * 64 + j;
    const int gch = b * HIDn + i;
    const int t0 = chunk * CH;
    const int t1 = t0 + CH - 1;

    const float* u2 = u + (size_t)b * Ln * THIDn + c2;
    const float* u1 = u + (size_t)b * Ln * THIDn + c1;
    const float* uv = u + (size_t)b * Ln * THIDn + cv;
    float* op = out + (size_t)b * Ln * HIDn + i;
    const float w20 = sfw[c2 * 3 + 0], w21 = sfw[c2 * 3 + 1], w22 = 2.0f * sfw[c2 * 3 + 2];
    const float w10 = sfw[c1 * 3 + 0], w11 = sfw[c1 * 3 + 1], w12 = 2.0f * sfw[c1 * 3 + 2];
    const float wv0 = sfw[cv * 3 + 0], wv1 = sfw[cv * 3 + 1], wv2 = 2.0f * sfw[cv * 3 + 2];

    f32x2 p2[8];
#pragma unroll
    for (int s = 0; s < 8; ++s) p2[s] = (f32x2){expf(lp[2 * s]), expf(lp[2 * s + 1])};
    float rr[STATEn];
#pragma unroll
    for (int s = 0; s < STATEn; ++s) rr[s] = res[s];  // uniform -> s_load

    const size_t cbase = ((size_t)chunk * (Bn * HIDn) + gch) * 16;

    // ---- forward pass: causal branch, y_c -> out ----
    {
        f32x2 f2[8];
        const f32x2* cF2 = (const f32x2*)(carryF + cbase);
#pragma unroll
        for (int s = 0; s < 8; ++s) f2[s] = cF2[s];
        float a0 = ldu(u1, t0 - 2), a1 = ldu(u1, t0 - 1), a2 = ldu(u1, t0), a3 = ldu(u1, t0 + 1);
        float v0 = ldu(uv, t0 - 2), v1 = ldu(uv, t0 - 1), v2 = ldu(uv, t0), v3 = ldu(uv, t0 + 1);
#pragma unroll 8
        for (int tt = 0; tt < CH; ++tt) {
            const int t = t0 + tt;
            const float a4 = ldu(u1, t + 2);
            const float v4 = ldu(uv, t + 2);
            const float z1 = fmaf(w10, a0 + a4, fmaf(w11, a1 + a3, w12 * a2));
            const float zv = fmaf(wv0, v0 + v4, fmaf(wv1, v1 + v3, wv2 * v2));
            const float x = z1 * zv;
            const f32x2 xb = (f32x2){x, x};
#pragma unroll
            for (int s = 0; s < 8; ++s) f2[s] = __builtin_elementwise_fma(p2[s], f2[s], xb);
            float acc0 = rr[0] * f2[0].x, acc1 = rr[1] * f2[0].y;
            float acc2 = rr[2] * f2[1].x, acc3 = rr[3] * f2[1].y;
#pragma unroll
            for (int s = 2; s < 8; s += 2) {
                acc0 = fmaf(rr[2 * s + 0], f2[s].x, acc0);
                acc1 = fmaf(rr[2 * s + 1], f2[s].y, acc1);
                acc2 = fmaf(rr[2 * s + 2], f2[s + 1].x, acc2);
                acc3 = fmaf(rr[2 * s + 3], f2[s + 1].y, acc3);
            }
            op[(size_t)t * HIDn] = (acc0 + acc1) + (acc2 + acc3);
            a0 = a1; a1 = a2; a2 = a3; a3 = a4;
            v0 = v1; v1 = v2; v2 = v3; v3 = v4;
        }
    }

    // ---- backward pass: anti-causal branch + skip + gate, RMW out ----
    {
        f32x2 g2[8];
        const f32x2* cG2 = (const f32x2*)(carryG + cbase);
#pragma unroll
        for (int s = 0; s < 8; ++s) g2[s] = cG2[s];
        const float dI = Dp[i];
        float a4 = ldu(u1, t1 + 2), a3 = ldu(u1, t1 + 1), a2 = ldu(u1, t1), a1 = ldu(u1, t1 - 1);
        float v4 = ldu(uv, t1 + 2), v3 = ldu(uv, t1 + 1), v2 = ldu(uv, t1), v1 = ldu(uv, t1 - 1);
        float e4 = ldu(u2, t1 + 2), e3 = ldu(u2, t1 + 1), e2 = ldu(u2, t1), e1 = ldu(u2, t1 - 1);
#pragma unroll 8
        for (int tt = CH - 1; tt >= 0; --tt) {
            const int t = t0 + tt;
            const float yc = op[(size_t)t * HIDn];  // own earlier store; L2-hot
            const float a0 = ldu(u1, t - 2);
            const float v0 = ldu(uv, t - 2);
            const float e0 = ldu(u2, t - 2);
            const float z1 = fmaf(w10, a0 + a4, fmaf(w11, a1 + a3, w12 * a2));
            const float zv = fmaf(wv0, v0 + v4, fmaf(wv1, v1 + v3, wv2 * v2));
            const float z2 = fmaf(w20, e0 + e4, fmaf(w21, e1 + e3, w22 * e2));
            const float x = z1 * zv;
            const f32x2 xb = (f32x2){x, x};
#pragma unroll
            for (int s = 0; s < 8; ++s) g2[s] = __builtin_elementwise_fma(p2[s], g2[s], xb);
            float acc0 = rr[0] * g2[0].x, acc1 = rr[1] * g2[0].y;
            float acc2 = rr[2] * g2[1].x, acc3 = rr[3] * g2[1].y;
#pragma unroll
            for (int s = 2; s < 8; s += 2) {
                acc0 = fmaf(rr[2 * s + 0], g2[s].x, acc0);
                acc1 = fmaf(rr[2 * s + 1], g2[s].y, acc1);
                acc2 = fmaf(rr[2 * s + 2], g2[s + 1].x, acc2);
                acc3 = fmaf(rr[2 * s + 3], g2[s + 1].y, acc3);
            }
            const float ya = (acc0 + acc1) + (acc2 + acc3);
            op[(size_t)t * HIDn] = (yc + ya + dI * x) * z2;
            a4 = a3; a3 = a2; a2 = a1; a1 = a0;
            v4 = v3; v3 = v2; v2 = v1; v1 = v0;
            e4 = e3; e3 = e2; e2 = e1; e1 = e0;
        }
    }
}

template <int CH>
static void run_all(const float* u, const float* sfw, const float* lp,
                    const float* res, const float* Dp, float* out,
                    void* ws, hipStream_t stream) {
    constexpr int NC = Ln / CH;
    float* carryF = (float*)ws;
    float* carryG = carryF + (size_t)NC * (Bn * HIDn) * 16;
    dim3 grid(NC, HEADSn, Bn);
    hipLaunchKernelGGL((hyena_phaseA<CH>), grid, dim3(64), 0, stream,
                       u, sfw, lp, carryF, carryG);
    hipLaunchKernelGGL((hyena_phaseB<CH>), dim3(256), dim3(256), 0, stream,
                       lp, carryF, carryG);
    hipLaunchKernelGGL((hyena_phaseC<CH>), grid, dim3(64), 0, stream,
                       u, sfw, lp, res, Dp, carryF, carryG, out);
}

extern "C" void kernel_launch(void* const* d_in, const int* in_sizes, int n_in,
                              void* d_out, int out_size, void* d_ws, size_t ws_size,
                              hipStream_t stream) {
    const float* u   = (const float*)d_in[0];  // (B, L, 3*HID) fp32
    const float* sfw = (const float*)d_in[1];  // (3*HID, 1, 3)
    const float* lp  = (const float*)d_in[2];  // (1, 16, 1)
    const float* res = (const float*)d_in[3];  // (1, 16)
    const float* Dp  = (const float*)d_in[4];  // (HID,)
    float* out = (float*)d_out;                // (B, L, HID) fp32

    // carry workspace: NC * 2048 channels * 32 states * 4 B = 2^31/CH bytes
    const size_t need64 = ((size_t)1 << 31) / 64;  // 32 MiB at CH=64
    if (ws_size >= need64)            run_all<64>(u, sfw, lp, res, Dp, out, d_ws, stream);
    else if (ws_size >= need64 / 2)   run_all<128>(u, sfw, lp, res, Dp, out, d_ws, stream);
    else if (ws_size >= need64 / 4)   run_all<256>(u, sfw, lp, res, Dp, out, d_ws, stream);
    else                              run_all<512>(u, sfw, lp, res, Dp, out, d_ws, stream);
}